// Round 1
// baseline (2595.232 us; speedup 1.0000x reference)
//
#include <hip/hip_runtime.h>
#include <hip/hip_bf16.h>

constexpr int DIM   = 1024;
constexpr int HEADS = 8;
constexpr int HD    = 128;     // head dim
constexpr int SEQ   = 2048;
constexpr int BATCH = 4;
constexpr int BN_ROWS = BATCH * SEQ;          // 8192
// Reference multiplies scores by sqrt(head_dim) (replicating its bug exactly).
#define SCALE_F 11.3137084989847603904f

// ---------------------------------------------------------------------------
// GEMM: C[M,N] = A[M,K] * B[N,K]^T + bias[N]   (A,B,C row-major, f32)
// BM=BN=128, BK=16, 256 threads, 8x8 accumulator per thread.
// ---------------------------------------------------------------------------
__global__ __launch_bounds__(256)
void gemm_bias_kernel(const float* __restrict__ A, const float* __restrict__ B,
                      const float* __restrict__ bias, float* __restrict__ C,
                      int M, int N, int K)
{
    constexpr int BM = 128, BN = 128, BK = 16;
    __shared__ float As[BK][BM + 4];
    __shared__ float Bs[BK][BN + 4];

    const int tid = threadIdx.x;
    const int m0  = blockIdx.y * BM;
    const int n0  = blockIdx.x * BN;
    const int ty  = tid >> 4, tx = tid & 15;
    const int rm  = ty * 8,   cn = tx * 8;

    float acc[8][8];
#pragma unroll
    for (int i = 0; i < 8; ++i)
#pragma unroll
        for (int j = 0; j < 8; ++j) acc[i][j] = 0.f;

    for (int k0 = 0; k0 < K; k0 += BK) {
        // Stage A and B tiles: 128x16 f32 each = 512 float4, 2 per thread.
#pragma unroll
        for (int i = 0; i < 2; ++i) {
            const int e = (tid + i * 256) * 4;
            const int r = e >> 4;       // row in tile
            const int c = e & 15;       // col in tile (multiple of 4)
            float4 va = *(const float4*)&A[(size_t)(m0 + r) * K + k0 + c];
            As[c + 0][r] = va.x; As[c + 1][r] = va.y;
            As[c + 2][r] = va.z; As[c + 3][r] = va.w;
            float4 vb = *(const float4*)&B[(size_t)(n0 + r) * K + k0 + c];
            Bs[c + 0][r] = vb.x; Bs[c + 1][r] = vb.y;
            Bs[c + 2][r] = vb.z; Bs[c + 3][r] = vb.w;
        }
        __syncthreads();

#pragma unroll
        for (int kk = 0; kk < BK; ++kk) {
            float a[8], b[8];
            const float4* ap = (const float4*)&As[kk][rm];
            const float4* bp = (const float4*)&Bs[kk][cn];
            float4 a0 = ap[0], a1 = ap[1];
            float4 b0 = bp[0], b1 = bp[1];
            a[0]=a0.x; a[1]=a0.y; a[2]=a0.z; a[3]=a0.w;
            a[4]=a1.x; a[5]=a1.y; a[6]=a1.z; a[7]=a1.w;
            b[0]=b0.x; b[1]=b0.y; b[2]=b0.z; b[3]=b0.w;
            b[4]=b1.x; b[5]=b1.y; b[6]=b1.z; b[7]=b1.w;
#pragma unroll
            for (int i = 0; i < 8; ++i)
#pragma unroll
                for (int j = 0; j < 8; ++j)
                    acc[i][j] = fmaf(a[i], b[j], acc[i][j]);
        }
        __syncthreads();
    }

    // Epilogue: add bias, store float4.
    float bsv[8];
#pragma unroll
    for (int j = 0; j < 8; ++j) bsv[j] = bias[n0 + cn + j];
#pragma unroll
    for (int i = 0; i < 8; ++i) {
        size_t row = (size_t)(m0 + rm + i) * N + n0 + cn;
#pragma unroll
        for (int j = 0; j < 8; j += 4) {
            float4 v;
            v.x = acc[i][j + 0] + bsv[j + 0];
            v.y = acc[i][j + 1] + bsv[j + 1];
            v.z = acc[i][j + 2] + bsv[j + 2];
            v.w = acc[i][j + 3] + bsv[j + 3];
            *(float4*)&C[row + j] = v;
        }
    }
}

// ---------------------------------------------------------------------------
// Flash attention, f32.  qkv layout: [B, N, 3, H, HD] flat
//   q(b,n,h,d) = qkv[((b*SEQ+n)*3 + 0)*DIM + h*HD + d], k -> +1, v -> +2.
// One block = (b, h, 64-row Q tile). 256 threads = 4 waves.
// Thread (tq = tid&63, w = tid>>6): owns Q-row tq, output dims [w*32, w*32+32).
// K/V iterated in 32-row LDS tiles with online softmax.
// Output written as attn[b][n][h*HD + d]  (the reference's [B,N,C] transpose).
// ---------------------------------------------------------------------------
__global__ __launch_bounds__(256)
void attn_kernel(const float* __restrict__ qkv, float* __restrict__ outp)
{
    constexpr int QB = 64, KB = 32;
    __shared__ float Qs[QB][HD + 2];   // pad 130: 2-way bank alias (free), float2-aligned
    __shared__ float Ks[KB][HD];
    __shared__ float Vs[KB][HD];
    __shared__ float Ps[QB][KB + 1];   // pad 33: conflict-free column reads
    __shared__ float redM[4][QB];
    __shared__ float redS[4][QB];

    const int tid = threadIdx.x;
    const int tq  = tid & 63;
    const int w   = tid >> 6;
    const int qt  = blockIdx.x;        // q tile
    const int h   = blockIdx.y;
    const int b   = blockIdx.z;
    const int q0  = qt * QB;

    // ---- load Q tile (64 x 128 f32 = 2048 float4, 8 per thread) ----
#pragma unroll
    for (int i = 0; i < 8; ++i) {
        const int e = (tid + i * 256) * 4;
        const int r = e >> 7;
        const int d = e & 127;
        const size_t src = ((size_t)(b * SEQ + q0 + r) * 3 + 0) * DIM + h * HD + d;
        float4 v = *(const float4*)&qkv[src];
        Qs[r][d + 0] = v.x; Qs[r][d + 1] = v.y;
        Qs[r][d + 2] = v.z; Qs[r][d + 3] = v.w;
    }

    float m = -INFINITY, l = 0.f;
    float4 o4[8];
#pragma unroll
    for (int i = 0; i < 8; ++i) o4[i] = make_float4(0.f, 0.f, 0.f, 0.f);

    for (int kt = 0; kt < SEQ / KB; ++kt) {
        __syncthreads();   // previous iteration done with Ks/Vs/Ps (also covers Q load, iter 0)

        // ---- load K,V tiles (32 x 128 each = 1024 float4, 4 per thread each) ----
#pragma unroll
        for (int i = 0; i < 4; ++i) {
            const int e = (tid + i * 256) * 4;
            const int r = e >> 7;
            const int d = e & 127;
            const size_t base = ((size_t)(b * SEQ + kt * KB + r) * 3) * DIM + h * HD + d;
            *(float4*)&Ks[r][d] = *(const float4*)&qkv[base + 1 * DIM];
            *(float4*)&Vs[r][d] = *(const float4*)&qkv[base + 2 * DIM];
        }
        __syncthreads();

        // ---- scores: this thread computes s[j] for k = w*8 + j, row tq ----
        float s[8];
#pragma unroll
        for (int j = 0; j < 8; ++j) s[j] = 0.f;
        const float2* qrow = (const float2*)&Qs[tq][0];
#pragma unroll 8
        for (int d2 = 0; d2 < HD / 2; ++d2) {
            const float2 qv = qrow[d2];
#pragma unroll
            for (int j = 0; j < 8; ++j) {
                const float2 kv = ((const float2*)&Ks[w * 8 + j][0])[d2];
                s[j] = fmaf(qv.x, kv.x, s[j]);
                s[j] = fmaf(qv.y, kv.y, s[j]);
            }
        }
        float tmax = -INFINITY;
#pragma unroll
        for (int j = 0; j < 8; ++j) {
            s[j] *= SCALE_F;
            tmax = fmaxf(tmax, s[j]);
        }
        redM[w][tq] = tmax;
        __syncthreads();

        const float m_new = fmaxf(fmaxf(fmaxf(redM[0][tq], redM[1][tq]),
                                        fmaxf(redM[2][tq], redM[3][tq])), m);
        const float alpha = __expf(m - m_new);
        float psum = 0.f;
#pragma unroll
        for (int j = 0; j < 8; ++j) {
            const float p = __expf(s[j] - m_new);
            Ps[tq][w * 8 + j] = p;
            psum += p;
        }
        redS[w][tq] = psum;
        __syncthreads();

        l = l * alpha + (redS[0][tq] + redS[1][tq] + redS[2][tq] + redS[3][tq]);
        m = m_new;
#pragma unroll
        for (int i = 0; i < 8; ++i) {
            o4[i].x *= alpha; o4[i].y *= alpha; o4[i].z *= alpha; o4[i].w *= alpha;
        }

        // ---- PV: o[d] += sum_k P[tq][k] * V[k][d], d in [w*32, w*32+32) ----
#pragma unroll 4
        for (int k = 0; k < KB; ++k) {
            const float pv = Ps[tq][k];
            const float4* vrow = (const float4*)&Vs[k][w * 32];
#pragma unroll
            for (int i = 0; i < 8; ++i) {
                const float4 vv = vrow[i];
                o4[i].x = fmaf(pv, vv.x, o4[i].x);
                o4[i].y = fmaf(pv, vv.y, o4[i].y);
                o4[i].z = fmaf(pv, vv.z, o4[i].z);
                o4[i].w = fmaf(pv, vv.w, o4[i].w);
            }
        }
    }

    // ---- epilogue: normalize and write attn[b][q0+tq][h*HD + w*32 + i*4] ----
    const float rl = 1.f / l;
    const size_t dst = (size_t)(b * SEQ + q0 + tq) * DIM + h * HD + w * 32;
#pragma unroll
    for (int i = 0; i < 8; ++i) {
        float4 v;
        v.x = o4[i].x * rl; v.y = o4[i].y * rl;
        v.z = o4[i].z * rl; v.w = o4[i].w * rl;
        *(float4*)&outp[dst + i * 4] = v;
    }
}

// ---------------------------------------------------------------------------
extern "C" void kernel_launch(void* const* d_in, const int* in_sizes, int n_in,
                              void* d_out, int out_size, void* d_ws, size_t ws_size,
                              hipStream_t stream)
{
    const float* x     = (const float*)d_in[0];  // [4,2048,1024]
    const float* W_qkv = (const float*)d_in[1];  // [3072,1024]
    const float* b_qkv = (const float*)d_in[2];  // [3072]
    const float* W0    = (const float*)d_in[3];  // [1024,1024]
    const float* b0    = (const float*)d_in[4];  // [1024]
    float* out = (float*)d_out;                  // [4,2048,1024]

    float* qkv  = (float*)d_ws;                                          // 8192*3072 f32
    float* attn = (float*)((char*)d_ws + (size_t)BN_ROWS * 3 * DIM * 4); // 8192*1024 f32

    // 1) QKV projection: [8192,1024] x [3072,1024]^T + bias -> [8192,3072]
    gemm_bias_kernel<<<dim3(3 * DIM / 128, BN_ROWS / 128), 256, 0, stream>>>(
        x, W_qkv, b_qkv, qkv, BN_ROWS, 3 * DIM, DIM);

    // 2) attention -> attn [8192,1024] (already in [B,N,H*HD] layout)
    attn_kernel<<<dim3(SEQ / 64, HEADS, BATCH), 256, 0, stream>>>(qkv, attn);

    // 3) output projection: [8192,1024] x [1024,1024]^T + bias -> out
    gemm_bias_kernel<<<dim3(DIM / 128, BN_ROWS / 128), 256, 0, stream>>>(
        attn, W0, b0, out, BN_ROWS, DIM, DIM);
}

// Round 5
// 843.148 us; speedup vs baseline: 3.0780x; 3.0780x over previous
//
#include <hip/hip_runtime.h>
#include <hip/hip_bf16.h>

constexpr int DIM   = 1024;
constexpr int HEADS = 8;
constexpr int HD    = 128;     // head dim
constexpr int SEQ   = 2048;
constexpr int BATCH = 4;
constexpr int BN_ROWS = BATCH * SEQ;          // 8192
// Reference multiplies scores by sqrt(head_dim) (replicating its bug exactly).
#define SCALE_F 11.3137084989847603904f

typedef __attribute__((ext_vector_type(8))) short  short8;
typedef __attribute__((ext_vector_type(8))) ushort u16x8;
typedef __attribute__((ext_vector_type(4))) float  f32x4;

// ---------------------------------------------------------------------------
// bf16 helpers
// ---------------------------------------------------------------------------
__device__ __forceinline__ ushort split_hi(float x, float& rem) {
    // truncation split: hi = top-16 bits of x; rem = x - hi (exact)
    unsigned xb = __builtin_bit_cast(unsigned, x);
    unsigned hb = xb & 0xFFFF0000u;
    rem = x - __builtin_bit_cast(float, hb);
    return (ushort)(xb >> 16);
}
__device__ __forceinline__ ushort rne16(float x) {
    unsigned xb = __builtin_bit_cast(unsigned, x);
    unsigned r  = xb + 0x7FFFu + ((xb >> 16) & 1u);
    return (ushort)(r >> 16);
}

// ---------------------------------------------------------------------------
// Split-bf16 MFMA GEMM: C[M,N] = A[M,K]*B[N,K]^T + bias[N]  (all f32 in memory)
// A,B split per element into hi (trunc bf16) + lo (rne bf16 of remainder);
// C ≈ Ah·Bh + Ah·Bl + Al·Bh  (dropped Al·Bl ~ 2^-16 relative — f32-class).
// 128x128 tile, BK=32, 256 thr / 4 waves (2x2 of 64x64), 4x4 16x16 frags/wave.
// LDS planes stride 40 bf16 (80 B) to spread banks.
// Frag contracts (same as attn kernel, m89-verified): A-frag lane&15 = row,
// k=(lane>>4)*8+j; B-frag lane&15 = out-col; D: col=lane&15, row=4*(lane>>4)+reg.
// ---------------------------------------------------------------------------
constexpr int GS = 40;   // LDS row stride in bf16 elems

__global__ __launch_bounds__(256)
void gemm_split_kernel(const float* __restrict__ A, const float* __restrict__ B,
                       const float* __restrict__ bias, float* __restrict__ C,
                       int M, int N, int K)
{
    __shared__ ushort Ah[128 * GS], Al[128 * GS];
    __shared__ ushort Bh[128 * GS], Bl[128 * GS];

    const int tid  = threadIdx.x;
    const int lane = tid & 63;
    const int w    = tid >> 6;
    const int l15  = lane & 15;
    const int g    = lane >> 4;

    // XCD-bijective swizzle (grid counts used here are multiples of 8)
    const int nbn   = N >> 7;
    const int nb    = (M >> 7) * nbn;
    const int chunk = nb >> 3;
    const int pid   = blockIdx.x;
    const int lb    = (pid & 7) * chunk + (pid >> 3);
    const int m0    = (lb / nbn) * 128;
    const int n0    = (lb % nbn) * 128;

    const int mw = (w >> 1) * 64;     // wave's sub-tile origin
    const int nw = (w & 1) * 64;

    // staging assignment: thread -> row (0..127), 16 consecutive k-cols
    const int srow = tid >> 1;
    const int scol = (tid & 1) * 16;

    f32x4 acc[4][4];
#pragma unroll
    for (int i = 0; i < 4; ++i)
#pragma unroll
        for (int j = 0; j < 4; ++j) acc[i][j] = (f32x4){0.f, 0.f, 0.f, 0.f};

    for (int k0 = 0; k0 < K; k0 += 32) {
        __syncthreads();
        // ---- stage A,B K-slab: load f32, split, write hi/lo planes ----
        {
            const float* Ap = &A[(size_t)(m0 + srow) * K + k0 + scol];
            const float* Bp = &B[(size_t)(n0 + srow) * K + k0 + scol];
            float av[16], bv[16];
#pragma unroll
            for (int i = 0; i < 4; ++i) {
                *(float4*)&av[i * 4] = *(const float4*)&Ap[i * 4];
                *(float4*)&bv[i * 4] = *(const float4*)&Bp[i * 4];
            }
#pragma unroll
            for (int hlf = 0; hlf < 2; ++hlf) {
                short8 HA, LA, HB, LB;
#pragma unroll
                for (int j = 0; j < 8; ++j) {
                    float r;
                    HA[j] = (short)split_hi(av[hlf * 8 + j], r);
                    LA[j] = (short)rne16(r);
                    HB[j] = (short)split_hi(bv[hlf * 8 + j], r);
                    LB[j] = (short)rne16(r);
                }
                const int off = srow * GS + scol + hlf * 8;
                *(short8*)&Ah[off] = HA;
                *(short8*)&Al[off] = LA;
                *(short8*)&Bh[off] = HB;
                *(short8*)&Bl[off] = LB;
            }
        }
        __syncthreads();

        // ---- 4x4 MFMA, 3 split products ----
        short8 a_h[4], a_l[4];
#pragma unroll
        for (int mi = 0; mi < 4; ++mi) {
            const int off = (mw + mi * 16 + l15) * GS + g * 8;
            a_h[mi] = *(const short8*)&Ah[off];
            a_l[mi] = *(const short8*)&Al[off];
        }
#pragma unroll
        for (int ni = 0; ni < 4; ++ni) {
            const int off = (nw + ni * 16 + l15) * GS + g * 8;
            short8 b_h = *(const short8*)&Bh[off];
            short8 b_l = *(const short8*)&Bl[off];
#pragma unroll
            for (int mi = 0; mi < 4; ++mi) {
                acc[mi][ni] = __builtin_amdgcn_mfma_f32_16x16x32_bf16(a_h[mi], b_h, acc[mi][ni], 0, 0, 0);
                acc[mi][ni] = __builtin_amdgcn_mfma_f32_16x16x32_bf16(a_l[mi], b_h, acc[mi][ni], 0, 0, 0);
                acc[mi][ni] = __builtin_amdgcn_mfma_f32_16x16x32_bf16(a_h[mi], b_l, acc[mi][ni], 0, 0, 0);
            }
        }
    }

    // ---- epilogue: bias + store ----
#pragma unroll
    for (int ni = 0; ni < 4; ++ni) {
        const int col = n0 + nw + ni * 16 + l15;
        const float bb = bias[col];
#pragma unroll
        for (int mi = 0; mi < 4; ++mi) {
            const int row = m0 + mw + mi * 16 + 4 * g;
#pragma unroll
            for (int r = 0; r < 4; ++r)
                C[(size_t)(row + r) * N + col] = acc[mi][ni][r] + bb;
        }
    }
}

// ---------------------------------------------------------------------------
// MFMA flash attention (byte-identical to R1).  qkv: [B,N,3,DIM] f32.
// ---------------------------------------------------------------------------
__global__ __launch_bounds__(256, 2)
void attn_mfma_kernel(const float* __restrict__ qkv, float* __restrict__ outp)
{
    constexpr int QB = 64, KB = 32;
    constexpr int VS = 40;                      // Vt / P row stride (elems)
    __shared__ ushort Khi[KB * HD];
    __shared__ ushort Kmid[KB * HD];
    __shared__ ushort Klo[KB * HD];
    __shared__ ushort Vt[HD * VS];              // V transposed: Vt[d][k]
    __shared__ ushort Pl[QB * VS];              // P[q][k]

    const int tid  = threadIdx.x;
    const int lane = tid & 63;
    const int w    = tid >> 6;
    const int l15  = lane & 15;
    const int g    = lane >> 4;                 // k-group

    // XCD-aware swizzle: 128 consecutive logical blocks (4 heads) per XCD
    const int pid = blockIdx.x;                 // 0..1023
    const int lb  = (pid & 7) * 128 + (pid >> 3);
    const int qt  = lb & 31;
    const int bh  = lb >> 5;
    const int h   = bh & 7, b = bh >> 3;
    const int q0  = qt * QB;

    // ---- Q -> registers: 3-split bf16 A-frags (row = 16w + l15) ----
    short8 qh[4], qm[4], ql[4];
    {
        const float* qbase =
            &qkv[((size_t)(b * SEQ + q0 + 16 * w + l15) * 3 + 0) * DIM + h * HD];
#pragma unroll
        for (int dc = 0; dc < 4; ++dc) {
            float4 x0 = *(const float4*)&qbase[dc * 32 + g * 8];
            float4 x1 = *(const float4*)&qbase[dc * 32 + g * 8 + 4];
            float xs[8] = {x0.x, x0.y, x0.z, x0.w, x1.x, x1.y, x1.z, x1.w};
            short8 H, M, L;
#pragma unroll
            for (int j = 0; j < 8; ++j) {
                float r1, r2;
                ushort h1 = split_hi(xs[j], r1);
                ushort m1 = split_hi(r1, r2);
                H[j] = (short)h1;
                M[j] = (short)m1;
                L[j] = (short)(ushort)(__builtin_bit_cast(unsigned, r2) >> 16);
            }
            qh[dc] = H; qm[dc] = M; ql[dc] = L;
        }
    }

    float m_st[4], l_st[4];
#pragma unroll
    for (int r = 0; r < 4; ++r) { m_st[r] = -INFINITY; l_st[r] = 0.f; }
    f32x4 o[8];
#pragma unroll
    for (int n = 0; n < 8; ++n) o[n] = (f32x4){0.f, 0.f, 0.f, 0.f};

    for (int kt = 0; kt < SEQ / KB; ++kt) {
        __syncthreads();    // previous iteration done reading K/Vt

        // ---- stage K (3-split, swizzled) ----
        {
            const int rk = tid >> 3;            // 0..31
            const int d0 = (tid & 7) * 16;
            const float* ks =
                &qkv[((size_t)(b * SEQ + kt * KB + rk) * 3 + 1) * DIM + h * HD + d0];
            float kx[16];
#pragma unroll
            for (int i = 0; i < 4; ++i)
                *(float4*)&kx[i * 4] = *(const float4*)&ks[i * 4];
            const int msk = (rk & 15) * 8;
#pragma unroll
            for (int c = 0; c < 2; ++c) {
                u16x8 H, M, L;
#pragma unroll
                for (int j = 0; j < 8; ++j) {
                    float r1, r2;
                    ushort h1 = split_hi(kx[c * 8 + j], r1);
                    ushort m1 = split_hi(r1, r2);
                    H[j] = h1; M[j] = m1;
                    L[j] = (ushort)(__builtin_bit_cast(unsigned, r2) >> 16);
                }
                const int off = rk * HD + ((d0 + c * 8) ^ msk);
                *(u16x8*)&Khi[off]  = H;
                *(u16x8*)&Kmid[off] = M;
                *(u16x8*)&Klo[off]  = L;
            }
        }
        // ---- stage V transposed (bf16 RNE), pairs of k packed per dword ----
        {
            const int kv0 = (tid & 15) * 2;     // 0..30
            const int dv0 = (tid >> 4) * 8;     // 0..120
            const float* v0 =
                &qkv[((size_t)(b * SEQ + kt * KB + kv0) * 3 + 2) * DIM + h * HD + dv0];
            const float* v1 = v0 + 3 * DIM;
            float4 a0 = *(const float4*)&v0[0], a1 = *(const float4*)&v0[4];
            float4 b0 = *(const float4*)&v1[0], b1 = *(const float4*)&v1[4];
            float va[8] = {a0.x, a0.y, a0.z, a0.w, a1.x, a1.y, a1.z, a1.w};
            float vb[8] = {b0.x, b0.y, b0.z, b0.w, b1.x, b1.y, b1.z, b1.w};
#pragma unroll
            for (int i = 0; i < 8; ++i) {
                unsigned pk = (unsigned)rne16(va[i]) | ((unsigned)rne16(vb[i]) << 16);
                *(unsigned*)&Vt[(dv0 + i) * VS + kv0] = pk;
            }
        }
        __syncthreads();

        // ---- QK^T: S[16w..][32k], 6 split-products, acc f32 ----
        f32x4 sacc[2];
        sacc[0] = (f32x4){0.f, 0.f, 0.f, 0.f};
        sacc[1] = (f32x4){0.f, 0.f, 0.f, 0.f};
#pragma unroll
        for (int dc = 0; dc < 4; ++dc) {
            const int soff = dc * 32 + g * 8;
            const int sw   = soff ^ (l15 * 8);
#pragma unroll
            for (int n = 0; n < 2; ++n) {
                const int off = (n * 16 + l15) * HD + sw;
                short8 bh = *(const short8*)&Khi[off];
                short8 bm = *(const short8*)&Kmid[off];
                short8 bl = *(const short8*)&Klo[off];
                sacc[n] = __builtin_amdgcn_mfma_f32_16x16x32_bf16(qh[dc], bh, sacc[n], 0, 0, 0);
                sacc[n] = __builtin_amdgcn_mfma_f32_16x16x32_bf16(qh[dc], bm, sacc[n], 0, 0, 0);
                sacc[n] = __builtin_amdgcn_mfma_f32_16x16x32_bf16(qm[dc], bh, sacc[n], 0, 0, 0);
                sacc[n] = __builtin_amdgcn_mfma_f32_16x16x32_bf16(qm[dc], bm, sacc[n], 0, 0, 0);
                sacc[n] = __builtin_amdgcn_mfma_f32_16x16x32_bf16(qh[dc], bl, sacc[n], 0, 0, 0);
                sacc[n] = __builtin_amdgcn_mfma_f32_16x16x32_bf16(ql[dc], bh, sacc[n], 0, 0, 0);
            }
        }

        // ---- online softmax (rows = 4g..4g+3 via reg index) ----
        float alpha[4];
#pragma unroll
        for (int r = 0; r < 4; ++r) {
            float s0 = sacc[0][r] * SCALE_F;
            float s1 = sacc[1][r] * SCALE_F;
            float mx = fmaxf(s0, s1);
            mx = fmaxf(mx, __shfl_xor(mx, 1));
            mx = fmaxf(mx, __shfl_xor(mx, 2));
            mx = fmaxf(mx, __shfl_xor(mx, 4));
            mx = fmaxf(mx, __shfl_xor(mx, 8));
            const float mnew = fmaxf(m_st[r], mx);
            alpha[r] = __expf(m_st[r] - mnew);
            const float p0 = __expf(s0 - mnew);
            const float p1 = __expf(s1 - mnew);
            const int prow = 16 * w + 4 * g + r;
            Pl[prow * VS + l15]      = rne16(p0);
            Pl[prow * VS + 16 + l15] = rne16(p1);
            float ps = p0 + p1;
            ps += __shfl_xor(ps, 1);
            ps += __shfl_xor(ps, 2);
            ps += __shfl_xor(ps, 4);
            ps += __shfl_xor(ps, 8);
            l_st[r] = l_st[r] * alpha[r] + ps;
            m_st[r] = mnew;
        }
#pragma unroll
        for (int n = 0; n < 8; ++n)
#pragma unroll
            for (int r = 0; r < 4; ++r) o[n][r] *= alpha[r];

        // ---- PV: A = P (own 16 q-rows), B = Vt ----
        short8 pa = *(const short8*)&Pl[(16 * w + l15) * VS + g * 8];
#pragma unroll
        for (int n = 0; n < 8; ++n) {
            short8 vbf = *(const short8*)&Vt[(n * 16 + l15) * VS + g * 8];
            o[n] = __builtin_amdgcn_mfma_f32_16x16x32_bf16(pa, vbf, o[n], 0, 0, 0);
        }
    }

    // ---- epilogue ----
    float rl[4];
#pragma unroll
    for (int r = 0; r < 4; ++r) rl[r] = 1.f / l_st[r];
    const size_t orow0 = (size_t)(b * SEQ + q0 + 16 * w + 4 * g);
#pragma unroll
    for (int n = 0; n < 8; ++n)
#pragma unroll
        for (int r = 0; r < 4; ++r)
            outp[(orow0 + r) * DIM + h * HD + n * 16 + l15] = o[n][r] * rl[r];
}

// ---------------------------------------------------------------------------
extern "C" void kernel_launch(void* const* d_in, const int* in_sizes, int n_in,
                              void* d_out, int out_size, void* d_ws, size_t ws_size,
                              hipStream_t stream)
{
    const float* x     = (const float*)d_in[0];
    const float* W_qkv = (const float*)d_in[1];
    const float* b_qkv = (const float*)d_in[2];
    const float* W0    = (const float*)d_in[3];
    const float* b0    = (const float*)d_in[4];
    float* out = (float*)d_out;

    float* qkv  = (float*)d_ws;                                          // 8192*3072 f32
    float* attn = (float*)((char*)d_ws + (size_t)BN_ROWS * 3 * DIM * 4); // 8192*1024 f32

    // 1) QKV projection: [8192,1024] x [3072,1024]^T + bias  (1536 blocks)
    gemm_split_kernel<<<dim3((BN_ROWS / 128) * (3 * DIM / 128)), 256, 0, stream>>>(
        x, W_qkv, b_qkv, qkv, BN_ROWS, 3 * DIM, DIM);

    // 2) attention -> attn [8192,1024]
    attn_mfma_kernel<<<dim3(BATCH * HEADS * (SEQ / 64)), 256, 0, stream>>>(qkv, attn);

    // 3) output projection: [8192,1024] x [1024,1024]^T + bias  (512 blocks)
    gemm_split_kernel<<<dim3((BN_ROWS / 128) * (DIM / 128)), 256, 0, stream>>>(
        attn, W0, b0, out, BN_ROWS, DIM, DIM);
}

// Round 7
// 602.098 us; speedup vs baseline: 4.3103x; 1.4004x over previous
//
#include <hip/hip_runtime.h>
#include <hip/hip_bf16.h>

constexpr int DIM   = 1024;
constexpr int HEADS = 8;
constexpr int HD    = 128;     // head dim
constexpr int SEQ   = 2048;
constexpr int BATCH = 4;
constexpr int BN_ROWS = BATCH * SEQ;          // 8192
// Reference multiplies scores by sqrt(head_dim) (replicating its bug exactly).
#define SCALE_F 11.3137084989847603904f

typedef __attribute__((ext_vector_type(8))) short  short8;
typedef __attribute__((ext_vector_type(8))) ushort u16x8;
typedef __attribute__((ext_vector_type(4))) float  f32x4;

// ---------------------------------------------------------------------------
// bf16 helpers
// ---------------------------------------------------------------------------
__device__ __forceinline__ ushort split_hi(float x, float& rem) {
    // truncation split: hi = top-16 bits of x; rem = x - hi (exact)
    unsigned xb = __builtin_bit_cast(unsigned, x);
    unsigned hb = xb & 0xFFFF0000u;
    rem = x - __builtin_bit_cast(float, hb);
    return (ushort)(xb >> 16);
}
__device__ __forceinline__ ushort rne16(float x) {
    unsigned xb = __builtin_bit_cast(unsigned, x);
    unsigned r  = xb + 0x7FFFu + ((xb >> 16) & 1u);
    return (ushort)(r >> 16);
}

// ---------------------------------------------------------------------------
// Split-bf16 MFMA GEMM (unchanged from R4 — measured ~267 us combined).
// ---------------------------------------------------------------------------
constexpr int GS = 40;   // LDS row stride in bf16 elems

__global__ __launch_bounds__(256)
void gemm_split_kernel(const float* __restrict__ A, const float* __restrict__ B,
                       const float* __restrict__ bias, float* __restrict__ C,
                       int M, int N, int K)
{
    __shared__ ushort Ah[128 * GS], Al[128 * GS];
    __shared__ ushort Bh[128 * GS], Bl[128 * GS];

    const int tid  = threadIdx.x;
    const int lane = tid & 63;
    const int w    = tid >> 6;
    const int l15  = lane & 15;
    const int g    = lane >> 4;

    const int nbn   = N >> 7;
    const int nb    = (M >> 7) * nbn;
    const int chunk = nb >> 3;
    const int pid   = blockIdx.x;
    const int lb    = (pid & 7) * chunk + (pid >> 3);
    const int m0    = (lb / nbn) * 128;
    const int n0    = (lb % nbn) * 128;

    const int mw = (w >> 1) * 64;
    const int nw = (w & 1) * 64;

    const int srow = tid >> 1;
    const int scol = (tid & 1) * 16;

    f32x4 acc[4][4];
#pragma unroll
    for (int i = 0; i < 4; ++i)
#pragma unroll
        for (int j = 0; j < 4; ++j) acc[i][j] = (f32x4){0.f, 0.f, 0.f, 0.f};

    for (int k0 = 0; k0 < K; k0 += 32) {
        __syncthreads();
        {
            const float* Ap = &A[(size_t)(m0 + srow) * K + k0 + scol];
            const float* Bp = &B[(size_t)(n0 + srow) * K + k0 + scol];
            float av[16], bv[16];
#pragma unroll
            for (int i = 0; i < 4; ++i) {
                *(float4*)&av[i * 4] = *(const float4*)&Ap[i * 4];
                *(float4*)&bv[i * 4] = *(const float4*)&Bp[i * 4];
            }
#pragma unroll
            for (int hlf = 0; hlf < 2; ++hlf) {
                short8 HA, LA, HB, LB;
#pragma unroll
                for (int j = 0; j < 8; ++j) {
                    float r;
                    HA[j] = (short)split_hi(av[hlf * 8 + j], r);
                    LA[j] = (short)rne16(r);
                    HB[j] = (short)split_hi(bv[hlf * 8 + j], r);
                    LB[j] = (short)rne16(r);
                }
                const int off = srow * GS + scol + hlf * 8;
                *(short8*)&Ah[off] = HA;
                *(short8*)&Al[off] = LA;
                *(short8*)&Bh[off] = HB;
                *(short8*)&Bl[off] = LB;
            }
        }
        __syncthreads();

        short8 a_h[4], a_l[4];
#pragma unroll
        for (int mi = 0; mi < 4; ++mi) {
            const int off = (mw + mi * 16 + l15) * GS + g * 8;
            a_h[mi] = *(const short8*)&Ah[off];
            a_l[mi] = *(const short8*)&Al[off];
        }
#pragma unroll
        for (int ni = 0; ni < 4; ++ni) {
            const int off = (nw + ni * 16 + l15) * GS + g * 8;
            short8 b_h = *(const short8*)&Bh[off];
            short8 b_l = *(const short8*)&Bl[off];
#pragma unroll
            for (int mi = 0; mi < 4; ++mi) {
                acc[mi][ni] = __builtin_amdgcn_mfma_f32_16x16x32_bf16(a_h[mi], b_h, acc[mi][ni], 0, 0, 0);
                acc[mi][ni] = __builtin_amdgcn_mfma_f32_16x16x32_bf16(a_l[mi], b_h, acc[mi][ni], 0, 0, 0);
                acc[mi][ni] = __builtin_amdgcn_mfma_f32_16x16x32_bf16(a_h[mi], b_l, acc[mi][ni], 0, 0, 0);
            }
        }
    }

#pragma unroll
    for (int ni = 0; ni < 4; ++ni) {
        const int col = n0 + nw + ni * 16 + l15;
        const float bb = bias[col];
#pragma unroll
        for (int mi = 0; mi < 4; ++mi) {
            const int row = m0 + mw + mi * 16 + 4 * g;
#pragma unroll
            for (int r = 0; r < 4; ++r)
                C[(size_t)(row + r) * N + col] = acc[mi][ni][r] + bb;
        }
    }
}

// ---------------------------------------------------------------------------
// MFMA flash attention v2.  qkv: [B,N,3,DIM] f32.  out: [B,N,DIM] f32.
// Block = (b,h,64 q-rows); 256 thr / 4 waves; KB=64 keys per phase (NT=32).
// Q in regs as 2-way bf16 split; K 2 swizzled LDS planes (hi/lo);
// QK^T = 3 MFMA products (err ~2^-16 rel). V transposed bf16 (VS=72, odd
// 16B-slot count -> balanced banks). T14: global loads for tile t+1 issued
// before compute of tile t; convert+ds_write next iteration. T5 setprio.
// Frag contracts (m89, verified R1/R5): A-frag row=lane&15, k=(lane>>4)*8+j;
// B-frag col=lane&15; D: col=lane&15, row=4*(lane>>4)+reg.
// ---------------------------------------------------------------------------
__global__ __launch_bounds__(256, 2)
void attn_mfma_kernel(const float* __restrict__ qkv, float* __restrict__ outp)
{
    constexpr int QB = 64, KB = 64, NT = SEQ / KB;   // 32 iterations
    constexpr int VS = 72;                           // Vt/Pl stride (144 B = 9 slots)
    __shared__ ushort Khi[KB * HD];                  // 16 KB
    __shared__ ushort Klo[KB * HD];                  // 16 KB
    __shared__ ushort Vt[HD * VS];                   // 18 KB  Vt[d][k]
    __shared__ ushort Pl[QB * VS];                   // 9 KB   P[q][k]

    const int tid  = threadIdx.x;
    const int lane = tid & 63;
    const int w    = tid >> 6;
    const int l15  = lane & 15;
    const int g    = lane >> 4;

    // XCD-aware swizzle (1024 blocks = 8 XCDs x 128)
    const int pid = blockIdx.x;
    const int lb  = (pid & 7) * 128 + (pid >> 3);
    const int qt  = lb & 31;
    const int bh_ = lb >> 5;
    const int h   = bh_ & 7, b = bh_ >> 3;
    const int q0  = qt * QB;

    // ---- Q -> registers: 2-way split A-frags (row = 16w + l15) ----
    short8 qh[4], qlo[4];
    {
        const float* qbase =
            &qkv[((size_t)(b * SEQ + q0 + 16 * w + l15) * 3 + 0) * DIM + h * HD];
#pragma unroll
        for (int dc = 0; dc < 4; ++dc) {
            float4 x0 = *(const float4*)&qbase[dc * 32 + g * 8];
            float4 x1 = *(const float4*)&qbase[dc * 32 + g * 8 + 4];
            float xs[8] = {x0.x, x0.y, x0.z, x0.w, x1.x, x1.y, x1.z, x1.w};
            short8 H, L;
#pragma unroll
            for (int j = 0; j < 8; ++j) {
                float r;
                H[j] = (short)split_hi(xs[j], r);
                L[j] = (short)rne16(r);
            }
            qh[dc] = H; qlo[dc] = L;
        }
    }

    // staging assignments
    const int krow = tid >> 2;              // 0..63
    const int kc0  = (tid & 3) * 32;        // 0,32,64,96
    const int vk0  = (tid & 31) * 2;        // 0..62
    const int vd0  = (tid >> 5) * 16;       // 0..112

    const size_t kgbase = ((size_t)(b * SEQ) * 3 + 1) * DIM + h * HD;
    const size_t vgbase = ((size_t)(b * SEQ) * 3 + 2) * DIM + h * HD;

    float4 kld[8], vld[8];
    // prologue: load tile 0
    {
        const float* kp = &qkv[kgbase + (size_t)krow * 3 * DIM + kc0];
#pragma unroll
        for (int i = 0; i < 8; ++i) kld[i] = *(const float4*)&kp[i * 4];
        const float* vp = &qkv[vgbase + (size_t)vk0 * 3 * DIM + vd0];
#pragma unroll
        for (int i = 0; i < 4; ++i) {
            vld[i]     = *(const float4*)&vp[i * 4];
            vld[4 + i] = *(const float4*)&vp[3 * DIM + i * 4];
        }
    }

    float m_st[4], l_st[4];
#pragma unroll
    for (int r = 0; r < 4; ++r) { m_st[r] = -INFINITY; l_st[r] = 0.f; }
    f32x4 o[8];
#pragma unroll
    for (int n = 0; n < 8; ++n) o[n] = (f32x4){0.f, 0.f, 0.f, 0.f};

    const int kmsk = (krow & 15) * 8;

    for (int kt = 0; kt < NT; ++kt) {
        // ---- convert regs (tile kt) -> LDS ----
#pragma unroll
        for (int c = 0; c < 4; ++c) {
            const float* kx = (const float*)&kld[c * 2];
            short8 H, L;
#pragma unroll
            for (int j = 0; j < 8; ++j) {
                float r;
                H[j] = (short)split_hi(kx[j], r);
                L[j] = (short)rne16(r);
            }
            const int off = krow * HD + ((kc0 + c * 8) ^ kmsk);
            *(short8*)&Khi[off] = H;
            *(short8*)&Klo[off] = L;
        }
        {
            const float* va = (const float*)&vld[0];
            const float* vb = (const float*)&vld[4];
#pragma unroll
            for (int i = 0; i < 16; ++i) {
                unsigned pk = (unsigned)rne16(va[i]) | ((unsigned)rne16(vb[i]) << 16);
                *(unsigned*)&Vt[(vd0 + i) * VS + vk0] = pk;
            }
        }
        __syncthreads();

        // ---- T14: issue next tile's global loads (overlap with compute) ----
        if (kt + 1 < NT) {
            const float* kp = &qkv[kgbase + (size_t)((kt + 1) * KB + krow) * 3 * DIM + kc0];
#pragma unroll
            for (int i = 0; i < 8; ++i) kld[i] = *(const float4*)&kp[i * 4];
            const float* vp = &qkv[vgbase + (size_t)((kt + 1) * KB + vk0) * 3 * DIM + vd0];
#pragma unroll
            for (int i = 0; i < 4; ++i) {
                vld[i]     = *(const float4*)&vp[i * 4];
                vld[4 + i] = *(const float4*)&vp[3 * DIM + i * 4];
            }
        }

        // ---- QK^T: S[16w+.. , 64k], 3 split products ----
        f32x4 sacc[4];
#pragma unroll
        for (int n = 0; n < 4; ++n) sacc[n] = (f32x4){0.f, 0.f, 0.f, 0.f};
        __builtin_amdgcn_s_setprio(1);
#pragma unroll
        for (int dc = 0; dc < 4; ++dc) {
            const int sw = (dc * 32 + g * 8) ^ (l15 * 8);
#pragma unroll
            for (int n = 0; n < 4; ++n) {
                const int off = (n * 16 + l15) * HD + sw;
                short8 kh = *(const short8*)&Khi[off];
                short8 kl = *(const short8*)&Klo[off];
                sacc[n] = __builtin_amdgcn_mfma_f32_16x16x32_bf16(qh[dc], kh, sacc[n], 0, 0, 0);
                sacc[n] = __builtin_amdgcn_mfma_f32_16x16x32_bf16(qh[dc], kl, sacc[n], 0, 0, 0);
                sacc[n] = __builtin_amdgcn_mfma_f32_16x16x32_bf16(qlo[dc], kh, sacc[n], 0, 0, 0);
            }
        }
        __builtin_amdgcn_s_setprio(0);

        // ---- online softmax (rows 16w + 4g + r) ----
        float alpha[4];
#pragma unroll
        for (int r = 0; r < 4; ++r) {
            float s0 = sacc[0][r] * SCALE_F;
            float s1 = sacc[1][r] * SCALE_F;
            float s2 = sacc[2][r] * SCALE_F;
            float s3 = sacc[3][r] * SCALE_F;
            float mx = fmaxf(fmaxf(s0, s1), fmaxf(s2, s3));
            mx = fmaxf(mx, __shfl_xor(mx, 1));
            mx = fmaxf(mx, __shfl_xor(mx, 2));
            mx = fmaxf(mx, __shfl_xor(mx, 4));
            mx = fmaxf(mx, __shfl_xor(mx, 8));
            const float mnew = fmaxf(m_st[r], mx);
            alpha[r] = __expf(m_st[r] - mnew);
            const float p0 = __expf(s0 - mnew);
            const float p1 = __expf(s1 - mnew);
            const float p2 = __expf(s2 - mnew);
            const float p3 = __expf(s3 - mnew);
            const int prow = (16 * w + 4 * g + r) * VS;
            Pl[prow + l15]      = rne16(p0);
            Pl[prow + 16 + l15] = rne16(p1);
            Pl[prow + 32 + l15] = rne16(p2);
            Pl[prow + 48 + l15] = rne16(p3);
            float ps = (p0 + p1) + (p2 + p3);
            ps += __shfl_xor(ps, 1);
            ps += __shfl_xor(ps, 2);
            ps += __shfl_xor(ps, 4);
            ps += __shfl_xor(ps, 8);
            l_st[r] = l_st[r] * alpha[r] + ps;
            m_st[r] = mnew;
        }
#pragma unroll
        for (int n = 0; n < 8; ++n)
#pragma unroll
            for (int r = 0; r < 4; ++r) o[n][r] *= alpha[r];

        // ---- PV: o[n] += P[rows] x Vt, k = 64 in 2 sub-frags ----
        __builtin_amdgcn_s_setprio(1);
#pragma unroll
        for (int ks = 0; ks < 2; ++ks) {
            short8 pa = *(const short8*)&Pl[(16 * w + l15) * VS + ks * 32 + g * 8];
#pragma unroll
            for (int n = 0; n < 8; ++n) {
                short8 vbf = *(const short8*)&Vt[(n * 16 + l15) * VS + ks * 32 + g * 8];
                o[n] = __builtin_amdgcn_mfma_f32_16x16x32_bf16(pa, vbf, o[n], 0, 0, 0);
            }
        }
        __builtin_amdgcn_s_setprio(0);
        __syncthreads();
    }

    // ---- epilogue ----
    float rl[4];
#pragma unroll
    for (int r = 0; r < 4; ++r) rl[r] = 1.f / l_st[r];
    const size_t orow0 = (size_t)(b * SEQ + q0 + 16 * w + 4 * g);
#pragma unroll
    for (int n = 0; n < 8; ++n)
#pragma unroll
        for (int r = 0; r < 4; ++r)
            outp[(orow0 + r) * DIM + h * HD + n * 16 + l15] = o[n][r] * rl[r];
}

// ---------------------------------------------------------------------------
extern "C" void kernel_launch(void* const* d_in, const int* in_sizes, int n_in,
                              void* d_out, int out_size, void* d_ws, size_t ws_size,
                              hipStream_t stream)
{
    const float* x     = (const float*)d_in[0];
    const float* W_qkv = (const float*)d_in[1];
    const float* b_qkv = (const float*)d_in[2];
    const float* W0    = (const float*)d_in[3];
    const float* b0    = (const float*)d_in[4];
    float* out = (float*)d_out;

    float* qkv  = (float*)d_ws;                                          // 8192*3072 f32
    float* attn = (float*)((char*)d_ws + (size_t)BN_ROWS * 3 * DIM * 4); // 8192*1024 f32

    gemm_split_kernel<<<dim3((BN_ROWS / 128) * (3 * DIM / 128)), 256, 0, stream>>>(
        x, W_qkv, b_qkv, qkv, BN_ROWS, 3 * DIM, DIM);

    attn_mfma_kernel<<<dim3(BATCH * HEADS * (SEQ / 64)), 256, 0, stream>>>(qkv, attn);

    gemm_split_kernel<<<dim3((BN_ROWS / 128) * (DIM / 128)), 256, 0, stream>>>(
        attn, W0, b0, out, BN_ROWS, DIM, DIM);
}